// Round 2
// baseline (457.308 us; speedup 1.0000x reference)
//
#include <hip/hip_runtime.h>

// Problem constants (fixed by reference)
constexpr int N_AG = 4096;   // N agents
constexpr int M_CL = 256;    // M clusters
constexpr int KD   = 32;     // K dim
constexpr float WEPS = 1e-6f;

constexpr int P_SPLIT = 4;            // n-splits per cluster in partial kernel
constexpr int PART_STRIDE = 1088;     // floats per (m,p) partial record: [S2(1024) | S1(32) | Z | count | pad]
constexpr int V_OFF = M_CL * P_SPLIT * PART_STRIDE;  // v starts here in ws (floats); 16B-aligned

__device__ __forceinline__ float rlane(float x, int l) {
    return __int_as_float(__builtin_amdgcn_readlane(__float_as_int(x), l));
}

// ---------------------------------------------------------------------------
// K1: batched 32x32 SPD solve  v_n = omega_child_n^{-1} mu_n
// One wave per matrix. Lane c owns column c (c=32 -> rhs b). Gauss-Jordan with
// pivot-row normalization; pivot column broadcast via v_readlane (static
// register indexing via full unroll). After 32 steps, lane 32 holds x.
// ---------------------------------------------------------------------------
__global__ __launch_bounds__(256) void solve_kernel(const float* __restrict__ oc,
                                                    const float* __restrict__ mu,
                                                    float* __restrict__ v) {
    const int lane = threadIdx.x & 63;
    const int wid  = threadIdx.x >> 6;
    const int idx  = blockIdx.x * 4 + wid;   // matrix id, 0..4095

    const int c = (lane < 32) ? lane : 32;   // lanes 33..63 mirror the b column (harmless)

    float col[32];
    #pragma unroll
    for (int i = 0; i < 32; ++i) {
        col[i] = (c < 32) ? oc[idx * 1024 + i * 32 + c]
                          : mu[idx * 32 + i];
    }

    #pragma unroll
    for (int j = 0; j < 32; ++j) {
        const float piv  = rlane(col[j], j);
        const float pinv = 1.0f / piv;
        col[j] *= pinv;                       // normalize pivot row (every column)
        #pragma unroll
        for (int i = 0; i < 32; ++i) {
            if (i == j) continue;
            const float fi = rlane(col[i], j);   // A[i][j] from lane j
            col[i] = fmaf(-fi, col[j], col[i]);
        }
    }

    // lane 32 now holds x_i in col[i]; distribute to lanes 0..31 and store.
    float res = 0.0f;
    #pragma unroll
    for (int i = 0; i < 32; ++i) {
        const float xi = rlane(col[i], 32);
        if (lane == i) res = xi;
    }
    if (lane < 32) v[idx * 32 + lane] = res;
}

// ---------------------------------------------------------------------------
// K2: partial weighted moments per (m, part).
//   S2 = sum_n w*v v^T, S1 = sum_n w*v, Z = sum w, count = sum mask
// grid = 1024 blocks (m = bid>>2, p = bid&3), 256 threads.
// Each thread accumulates an 8x8 tile of S2 over 1/16 of the n's (sub);
// the 16 sub-partials per tile are reduced at block end via 4 staging
// rounds through vbuf (wave r writes its subs' tiles, everyone accumulates
// its 4 owned output elements). This reduction was MISSING in round 1
// (16 threads raced writes to the same record -> absmax 79.6).
// v chunks staged in LDS with row stride 36 (16B-aligned, <=2-way banks).
// ---------------------------------------------------------------------------
__global__ __launch_bounds__(256, 3) void partial_kernel(const float* __restrict__ W,
                                                         const float* __restrict__ v,
                                                         float* __restrict__ wsout) {
    const int m = blockIdx.x >> 2;
    const int p = blockIdx.x & 3;
    const int t = threadIdx.x;

    __shared__ float vbuf[128 * 36];   // also reused as 4x1088 reduction stage
    __shared__ float wbuf[128];
    __shared__ float s1buf[32];
    __shared__ float red[256];

    const int tile = t & 15;
    const int sub  = t >> 4;
    const int k0 = (tile >> 2) * 8;
    const int l0 = (tile & 3) * 8;
    const bool do_s1 = ((tile & 3) == 0);   // tiles with l0==0 also accumulate S1 rows k0..k0+7

    float acc[8][8];
    #pragma unroll
    for (int r = 0; r < 8; ++r)
        #pragma unroll
        for (int cc = 0; cc < 8; ++cc) acc[r][cc] = 0.0f;
    float s1acc[8] = {0.f,0.f,0.f,0.f,0.f,0.f,0.f,0.f};
    float zacc = 0.0f, cacc = 0.0f;

    for (int ch = 0; ch < 8; ++ch) {
        const int n0 = p * 1024 + ch * 128;
        // stage 128x32 v values (coalesced global, conflict-free LDS stores)
        #pragma unroll
        for (int i = 0; i < 16; ++i) {
            const int g  = t + 256 * i;           // 0..4095
            const int nc = g >> 5, cc = g & 31;
            vbuf[nc * 36 + cc] = v[(size_t)(n0)*32 + g];
        }
        if (t < 128) {
            float wv = W[(size_t)(n0 + t) * 256 + m];
            const bool mk = (wv >= WEPS);
            wv = mk ? wv : 0.0f;
            wbuf[t] = wv;
            zacc += wv;
            cacc += mk ? 1.0f : 0.0f;
        }
        __syncthreads();

        const float4* vb4 = reinterpret_cast<const float4*>(vbuf);
        #pragma unroll
        for (int i = 0; i < 8; ++i) {
            const int nc = sub + 16 * i;
            const float w = wbuf[nc];
            const float4 a0 = vb4[nc * 9 + (k0 >> 2)];
            const float4 a1 = vb4[nc * 9 + (k0 >> 2) + 1];
            const float4 b0 = vb4[nc * 9 + (l0 >> 2)];
            const float4 b1 = vb4[nc * 9 + (l0 >> 2) + 1];
            float wa[8] = {w*a0.x, w*a0.y, w*a0.z, w*a0.w,
                           w*a1.x, w*a1.y, w*a1.z, w*a1.w};
            const float bb[8] = {b0.x, b0.y, b0.z, b0.w, b1.x, b1.y, b1.z, b1.w};
            #pragma unroll
            for (int r = 0; r < 8; ++r)
                #pragma unroll
                for (int cc = 0; cc < 8; ++cc)
                    acc[r][cc] = fmaf(wa[r], bb[cc], acc[r][cc]);
            if (do_s1) {
                #pragma unroll
                for (int r = 0; r < 8; ++r) s1acc[r] += wa[r];
            }
        }
        __syncthreads();
    }

    // ---- epilogue 1: reduce 16 sub-partials per tile through vbuf stage ----
    // Stage layout: slot s (=sub&3) stride 1088, tile stride 68 (float4-aligned).
    // Round r4: wave r4 (subs 4*r4..4*r4+3) overwrites the whole stage; then
    // every thread accumulates its 4 owned S2 elements from the 4 slots.
    const size_t base = (size_t)(m * 4 + p) * PART_STRIDE;
    const int sslot = sub & 3;
    const int k   = t >> 3;          // owned output row
    const int l0p = (t & 7) * 4;     // owned output col start
    const int eoff = ((k >> 3) * 4 + (l0p >> 3)) * 68 + (k & 7) * 8 + (l0p & 7);
    float fin0 = 0.f, fin1 = 0.f, fin2 = 0.f, fin3 = 0.f;

    #pragma unroll
    for (int r4 = 0; r4 < 4; ++r4) {
        if ((t >> 6) == r4) {
            float* dst = &vbuf[sslot * 1088 + tile * 68];
            #pragma unroll
            for (int r = 0; r < 8; ++r) {
                *reinterpret_cast<float4*>(&dst[r * 8])     =
                    make_float4(acc[r][0], acc[r][1], acc[r][2], acc[r][3]);
                *reinterpret_cast<float4*>(&dst[r * 8 + 4]) =
                    make_float4(acc[r][4], acc[r][5], acc[r][6], acc[r][7]);
            }
        }
        __syncthreads();
        #pragma unroll
        for (int s = 0; s < 4; ++s) {
            const float4 vv = *reinterpret_cast<const float4*>(&vbuf[s * 1088 + eoff]);
            fin0 += vv.x; fin1 += vv.y; fin2 += vv.z; fin3 += vv.w;
        }
        __syncthreads();
    }
    *reinterpret_cast<float4*>(&wsout[base + k * 32 + l0p]) =
        make_float4(fin0, fin1, fin2, fin3);

    // ---- epilogue 2: S1 / Z / count ----
    if (t < 32) s1buf[t] = 0.0f;
    __syncthreads();
    if (do_s1) {
        #pragma unroll
        for (int r = 0; r < 8; ++r) atomicAdd(&s1buf[k0 + r], s1acc[r]);
    }

    // Z reduction
    red[t] = zacc; __syncthreads();
    #pragma unroll
    for (int s = 128; s > 0; s >>= 1) {
        if (t < s) red[t] += red[t + s];
        __syncthreads();
    }
    if (t == 0) wsout[base + 1056] = red[0];
    __syncthreads();

    // count reduction
    red[t] = cacc; __syncthreads();
    #pragma unroll
    for (int s = 128; s > 0; s >>= 1) {
        if (t < s) red[t] += red[t + s];
        __syncthreads();
    }
    if (t == 0) wsout[base + 1057] = red[0];

    if (t < 32) wsout[base + 1024 + t] = s1buf[t];
}

// ---------------------------------------------------------------------------
// K3: combine. One block per m.
//   G = Omega_parent^T Omega_parent ; psi = tr(G S2)/Z - vbar^T G vbar
// ---------------------------------------------------------------------------
__global__ __launch_bounds__(256) void combine_kernel(const float* __restrict__ op,
                                                      const float* __restrict__ ws,
                                                      float* __restrict__ out) {
    const int m = blockIdx.x;
    const int t = threadIdx.x;

    __shared__ float omg[32 * 33];
    __shared__ float vbar[32];
    __shared__ float red[256];

    #pragma unroll
    for (int i = 0; i < 4; ++i) {
        const int g = t + 256 * i;
        const int r = g >> 5, cc = g & 31;
        omg[r * 33 + cc] = op[(size_t)m * 1024 + g];
    }

    const size_t mb = (size_t)m * 4 * PART_STRIDE;
    float Z = 0.0f, cnt = 0.0f, s1 = 0.0f;
    float s2[4] = {0.f, 0.f, 0.f, 0.f};
    #pragma unroll
    for (int p2 = 0; p2 < 4; ++p2) {
        const size_t bp = mb + (size_t)p2 * PART_STRIDE;
        Z   += ws[bp + 1056];
        cnt += ws[bp + 1057];
        if (t < 32) s1 += ws[bp + 1024 + t];
        const float4 sp = *reinterpret_cast<const float4*>(&ws[bp + t * 4]);
        s2[0] += sp.x; s2[1] += sp.y; s2[2] += sp.z; s2[3] += sp.w;
    }
    const float invZ = 1.0f / fmaxf(Z, 1e-30f);
    if (t < 32) vbar[t] = s1 * invZ;
    __syncthreads();

    const int k  = t >> 3;
    const int l0 = (t & 7) * 4;
    float G[4] = {0.f, 0.f, 0.f, 0.f};
    #pragma unroll
    for (int i = 0; i < 32; ++i) {
        const float ok = omg[i * 33 + k];
        #pragma unroll
        for (int q = 0; q < 4; ++q) G[q] = fmaf(ok, omg[i * 33 + l0 + q], G[q]);
    }

    const float vk = vbar[k];
    float val = 0.0f;
    #pragma unroll
    for (int q = 0; q < 4; ++q)
        val += G[q] * (s2[q] * invZ - vk * vbar[l0 + q]);

    red[t] = val; __syncthreads();
    #pragma unroll
    for (int s = 128; s > 0; s >>= 1) {
        if (t < s) red[t] += red[t + s];
        __syncthreads();
    }
    if (t == 0) out[m] = (cnt >= 1.5f) ? red[0] : 0.0f;
}

// ---------------------------------------------------------------------------
extern "C" void kernel_launch(void* const* d_in, const int* in_sizes, int n_in,
                              void* d_out, int out_size, void* d_ws, size_t ws_size,
                              hipStream_t stream) {
    const float* W  = (const float*)d_in[0];  // (4096, 256)
    const float* mu = (const float*)d_in[1];  // (4096, 32)
    const float* oc = (const float*)d_in[2];  // (4096, 32, 32)
    const float* op = (const float*)d_in[3];  // (256, 32, 32)
    float* out = (float*)d_out;               // (256,)
    float* ws  = (float*)d_ws;
    float* v   = ws + V_OFF;                  // (4096, 32) solved means

    solve_kernel<<<1024, 256, 0, stream>>>(oc, mu, v);
    partial_kernel<<<1024, 256, 0, stream>>>(W, v, ws);
    combine_kernel<<<256, 256, 0, stream>>>(op, ws, out);
}

// Round 3
// 134.842 us; speedup vs baseline: 3.3914x; 3.3914x over previous
//
#include <hip/hip_runtime.h>

// Problem constants (fixed by reference)
constexpr int N_AG = 4096;   // N agents
constexpr int M_CL = 256;    // M clusters
constexpr int KD   = 32;     // K dim
constexpr float WEPS = 1e-6f;

constexpr int P_SPLIT = 4;            // n-splits per cluster in partial kernel
constexpr int PART_STRIDE = 1088;     // floats per (m,p) partial record: [S2(1024) | S1(32) | Z | count | pad]
constexpr int V_OFF  = M_CL * P_SPLIT * PART_STRIDE;  // v (4096x32) at ws+V_OFF
constexpr int WT_OFF = V_OFF + N_AG * KD;             // Wt (256x4096, masked) at ws+WT_OFF
// total ws use: 1,114,112 + 131,072 + 1,048,576 floats = 9.2 MB

__device__ __forceinline__ float rlane(float x, int l) {
    return __int_as_float(__builtin_amdgcn_readlane(__float_as_int(x), l));
}

// ---------------------------------------------------------------------------
// K0: transpose + mask W: Wt[m][n] = (W[n][m] >= WEPS) ? W[n][m] : 0
// 32x32 LDS tiles; coalesced both directions. Masking here lets K2 derive
// count from (w >= WEPS) on the masked value (values >= 1e-6 are preserved).
// ---------------------------------------------------------------------------
__global__ __launch_bounds__(256) void transpose_kernel(const float* __restrict__ W,
                                                        float* __restrict__ Wt) {
    __shared__ float tb[32][33];
    const int x  = threadIdx.x & 31;
    const int y  = threadIdx.x >> 5;          // 0..7
    const int n0 = (blockIdx.x & 127) * 32;   // 4096/32 = 128 n-tiles
    const int m0 = (blockIdx.x >> 7) * 32;    // 256/32  = 8 m-tiles
    #pragma unroll
    for (int r = 0; r < 4; ++r) {
        const int n = y + 8 * r;
        float w = W[(size_t)(n0 + n) * 256 + m0 + x];
        tb[n][x] = (w >= WEPS) ? w : 0.0f;
    }
    __syncthreads();
    #pragma unroll
    for (int r = 0; r < 4; ++r) {
        const int mm = y + 8 * r;
        Wt[(size_t)(m0 + mm) * 4096 + n0 + x] = tb[x][mm];
    }
}

// ---------------------------------------------------------------------------
// K1: batched 32x32 SPD solve  v_n = omega_child_n^{-1} mu_n
// One wave per matrix; lane c owns column c (c=32 -> rhs). Gauss-Jordan with
// pivot broadcast via v_readlane (static reg indexing via full unroll).
// ---------------------------------------------------------------------------
__global__ __launch_bounds__(256) void solve_kernel(const float* __restrict__ oc,
                                                    const float* __restrict__ mu,
                                                    float* __restrict__ v) {
    const int lane = threadIdx.x & 63;
    const int wid  = threadIdx.x >> 6;
    const int idx  = blockIdx.x * 4 + wid;   // matrix id, 0..4095

    const int c = (lane < 32) ? lane : 32;   // lanes 33..63 mirror the rhs (harmless)

    float col[32];
    #pragma unroll
    for (int i = 0; i < 32; ++i) {
        col[i] = (c < 32) ? oc[idx * 1024 + i * 32 + c]
                          : mu[idx * 32 + i];
    }

    #pragma unroll
    for (int j = 0; j < 32; ++j) {
        const float piv  = rlane(col[j], j);
        const float pinv = 1.0f / piv;
        col[j] *= pinv;
        #pragma unroll
        for (int i = 0; i < 32; ++i) {
            if (i == j) continue;
            const float fi = rlane(col[i], j);
            col[i] = fmaf(-fi, col[j], col[i]);
        }
    }

    float res = 0.0f;
    #pragma unroll
    for (int i = 0; i < 32; ++i) {
        const float xi = rlane(col[i], 32);
        if (lane == i) res = xi;
    }
    if (lane < 32) v[idx * 32 + lane] = res;
}

// ---------------------------------------------------------------------------
// K2: partial weighted moments per (m, part).
//   S2 = sum_n w*v v^T, S1 = sum_n w*v, Z = sum w, count = sum (w>=eps)
// grid = 1024 blocks (m = bid>>2, p = bid&3), 256 threads.
// Thread owns an 8x8 S2 tile over 1/16 of n (sub); 16 sub-partials reduced
// at block end through vbuf staging (4 rounds).
// ROUND-3 FIX: round 2 spilled acc[8][8] to scratch (VGPR_Count=84,
// 505 MB scratch writes = 64 acc x 8 chunks x 256k threads, VALUBusy 5%).
// Cause: full unroll of the i-loop ballooned live fragments past the
// (256,3) budget. Now: launch_bounds(256,2) budget=256 regs + unroll 2,
// W pre-transposed/masked (coalesced float4), v staged as float4.
// ---------------------------------------------------------------------------
__global__ __launch_bounds__(256, 2) void partial_kernel(const float* __restrict__ Wt,
                                                         const float* __restrict__ v,
                                                         float* __restrict__ wsout) {
    const int m = blockIdx.x >> 2;
    const int p = blockIdx.x & 3;
    const int t = threadIdx.x;

    __shared__ float vbuf[128 * 36];   // stride 36: <=2-way banks; reused as reduction stage
    __shared__ float wbuf[1024];       // masked weights for this (m,p)
    __shared__ float s1buf[32];
    __shared__ float red[256];

    const int tile = t & 15;
    const int sub  = t >> 4;
    const int k0 = (tile >> 2) * 8;
    const int l0 = (tile & 3) * 8;
    const bool do_s1 = ((tile & 3) == 0);

    // ---- W phase: 1024 masked weights, coalesced float4 ----
    float zacc = 0.0f, cacc = 0.0f;
    {
        const float4 wv = reinterpret_cast<const float4*>(Wt + (size_t)m * 4096 + p * 1024)[t];
        zacc = wv.x + wv.y + wv.z + wv.w;
        cacc = (wv.x >= WEPS ? 1.f : 0.f) + (wv.y >= WEPS ? 1.f : 0.f)
             + (wv.z >= WEPS ? 1.f : 0.f) + (wv.w >= WEPS ? 1.f : 0.f);
        *reinterpret_cast<float4*>(&wbuf[t * 4]) = wv;
    }

    float acc[8][8];
    #pragma unroll
    for (int r = 0; r < 8; ++r)
        #pragma unroll
        for (int cc = 0; cc < 8; ++cc) acc[r][cc] = 0.0f;
    float s1acc[8] = {0.f,0.f,0.f,0.f,0.f,0.f,0.f,0.f};

    for (int ch = 0; ch < 8; ++ch) {
        const int n0 = p * 1024 + ch * 128;
        // stage 128x32 v values: coalesced float4 global loads
        const float4* vg4 = reinterpret_cast<const float4*>(v + (size_t)n0 * 32);
        #pragma unroll
        for (int i = 0; i < 4; ++i) {
            const int g4 = t + 256 * i;            // 0..1023 float4s
            const int nc = g4 >> 3, cc4 = (g4 & 7) * 4;
            *reinterpret_cast<float4*>(&vbuf[nc * 36 + cc4]) = vg4[g4];
        }
        __syncthreads();

        const float4* vb4 = reinterpret_cast<const float4*>(vbuf);
        #pragma unroll 2
        for (int i = 0; i < 8; ++i) {
            const int nc = sub + 16 * i;
            const float w = wbuf[ch * 128 + nc];
            const float4 a0 = vb4[nc * 9 + (k0 >> 2)];
            const float4 a1 = vb4[nc * 9 + (k0 >> 2) + 1];
            const float4 b0 = vb4[nc * 9 + (l0 >> 2)];
            const float4 b1 = vb4[nc * 9 + (l0 >> 2) + 1];
            float wa[8] = {w*a0.x, w*a0.y, w*a0.z, w*a0.w,
                           w*a1.x, w*a1.y, w*a1.z, w*a1.w};
            const float bb[8] = {b0.x, b0.y, b0.z, b0.w, b1.x, b1.y, b1.z, b1.w};
            #pragma unroll
            for (int r = 0; r < 8; ++r)
                #pragma unroll
                for (int cc = 0; cc < 8; ++cc)
                    acc[r][cc] = fmaf(wa[r], bb[cc], acc[r][cc]);
            if (do_s1) {
                #pragma unroll
                for (int r = 0; r < 8; ++r) s1acc[r] += wa[r];
            }
        }
        __syncthreads();
    }

    // ---- epilogue 1: reduce 16 sub-partials per tile through vbuf stage ----
    const size_t base = (size_t)(m * 4 + p) * PART_STRIDE;
    const int sslot = sub & 3;
    const int k   = t >> 3;          // owned output row
    const int l0p = (t & 7) * 4;     // owned output col start
    const int eoff = ((k >> 3) * 4 + (l0p >> 3)) * 68 + (k & 7) * 8 + (l0p & 7);
    float fin0 = 0.f, fin1 = 0.f, fin2 = 0.f, fin3 = 0.f;

    #pragma unroll
    for (int r4 = 0; r4 < 4; ++r4) {
        if ((t >> 6) == r4) {
            float* dst = &vbuf[sslot * 1088 + tile * 68];
            #pragma unroll
            for (int r = 0; r < 8; ++r) {
                *reinterpret_cast<float4*>(&dst[r * 8])     =
                    make_float4(acc[r][0], acc[r][1], acc[r][2], acc[r][3]);
                *reinterpret_cast<float4*>(&dst[r * 8 + 4]) =
                    make_float4(acc[r][4], acc[r][5], acc[r][6], acc[r][7]);
            }
        }
        __syncthreads();
        #pragma unroll
        for (int s = 0; s < 4; ++s) {
            const float4 vv = *reinterpret_cast<const float4*>(&vbuf[s * 1088 + eoff]);
            fin0 += vv.x; fin1 += vv.y; fin2 += vv.z; fin3 += vv.w;
        }
        __syncthreads();
    }
    *reinterpret_cast<float4*>(&wsout[base + k * 32 + l0p]) =
        make_float4(fin0, fin1, fin2, fin3);

    // ---- epilogue 2: S1 / Z / count ----
    if (t < 32) s1buf[t] = 0.0f;
    __syncthreads();
    if (do_s1) {
        #pragma unroll
        for (int r = 0; r < 8; ++r) atomicAdd(&s1buf[k0 + r], s1acc[r]);
    }

    red[t] = zacc; __syncthreads();
    #pragma unroll
    for (int s = 128; s > 0; s >>= 1) {
        if (t < s) red[t] += red[t + s];
        __syncthreads();
    }
    if (t == 0) wsout[base + 1056] = red[0];
    __syncthreads();

    red[t] = cacc; __syncthreads();
    #pragma unroll
    for (int s = 128; s > 0; s >>= 1) {
        if (t < s) red[t] += red[t + s];
        __syncthreads();
    }
    if (t == 0) wsout[base + 1057] = red[0];

    if (t < 32) wsout[base + 1024 + t] = s1buf[t];
}

// ---------------------------------------------------------------------------
// K3: combine. One block per m.
//   G = Omega_parent^T Omega_parent ; psi = tr(G S2)/Z - vbar^T G vbar
// ---------------------------------------------------------------------------
__global__ __launch_bounds__(256) void combine_kernel(const float* __restrict__ op,
                                                      const float* __restrict__ ws,
                                                      float* __restrict__ out) {
    const int m = blockIdx.x;
    const int t = threadIdx.x;

    __shared__ float omg[32 * 33];
    __shared__ float vbar[32];
    __shared__ float red[256];

    #pragma unroll
    for (int i = 0; i < 4; ++i) {
        const int g = t + 256 * i;
        const int r = g >> 5, cc = g & 31;
        omg[r * 33 + cc] = op[(size_t)m * 1024 + g];
    }

    const size_t mb = (size_t)m * 4 * PART_STRIDE;
    float Z = 0.0f, cnt = 0.0f, s1 = 0.0f;
    float s2[4] = {0.f, 0.f, 0.f, 0.f};
    #pragma unroll
    for (int p2 = 0; p2 < 4; ++p2) {
        const size_t bp = mb + (size_t)p2 * PART_STRIDE;
        Z   += ws[bp + 1056];
        cnt += ws[bp + 1057];
        if (t < 32) s1 += ws[bp + 1024 + t];
        const float4 sp = *reinterpret_cast<const float4*>(&ws[bp + t * 4]);
        s2[0] += sp.x; s2[1] += sp.y; s2[2] += sp.z; s2[3] += sp.w;
    }
    const float invZ = 1.0f / fmaxf(Z, 1e-30f);
    if (t < 32) vbar[t] = s1 * invZ;
    __syncthreads();

    const int k  = t >> 3;
    const int l0 = (t & 7) * 4;
    float G[4] = {0.f, 0.f, 0.f, 0.f};
    #pragma unroll
    for (int i = 0; i < 32; ++i) {
        const float ok = omg[i * 33 + k];
        #pragma unroll
        for (int q = 0; q < 4; ++q) G[q] = fmaf(ok, omg[i * 33 + l0 + q], G[q]);
    }

    const float vk = vbar[k];
    float val = 0.0f;
    #pragma unroll
    for (int q = 0; q < 4; ++q)
        val += G[q] * (s2[q] * invZ - vk * vbar[l0 + q]);

    red[t] = val; __syncthreads();
    #pragma unroll
    for (int s = 128; s > 0; s >>= 1) {
        if (t < s) red[t] += red[t + s];
        __syncthreads();
    }
    if (t == 0) out[m] = (cnt >= 1.5f) ? red[0] : 0.0f;
}

// ---------------------------------------------------------------------------
extern "C" void kernel_launch(void* const* d_in, const int* in_sizes, int n_in,
                              void* d_out, int out_size, void* d_ws, size_t ws_size,
                              hipStream_t stream) {
    const float* W  = (const float*)d_in[0];  // (4096, 256)
    const float* mu = (const float*)d_in[1];  // (4096, 32)
    const float* oc = (const float*)d_in[2];  // (4096, 32, 32)
    const float* op = (const float*)d_in[3];  // (256, 32, 32)
    float* out = (float*)d_out;               // (256,)
    float* ws  = (float*)d_ws;

    transpose_kernel<<<1024, 256, 0, stream>>>(W, ws + WT_OFF);
    solve_kernel<<<1024, 256, 0, stream>>>(oc, mu, ws + V_OFF);
    partial_kernel<<<1024, 256, 0, stream>>>(ws + WT_OFF, ws + V_OFF, ws);
    combine_kernel<<<256, 256, 0, stream>>>(op, ws, out);
}